// Round 2
// baseline (169.309 us; speedup 1.0000x reference)
//
#include <hip/hip_runtime.h>

// HolonomyAttention: out = softmax_causal((Q @ C_h) K^T / sqrt(D)) V
// B=2 H=16 T=2048 D=64, fp32 in/out.
// Round 11: r10 (parity split, halved L2 traffic) was latency-exposed at
// 2 blocks/CU. This round: strip-serial softmax/PV (peak liveness ~155
// regs), __launch_bounds__(256,3) -> 12 waves/CU, s_setprio around MFMA
// clusters, and branch-guarded tail prefetch (kills 67 MB of wasted L2
// reads from the old clamp).
// prep kernels unchanged.

typedef __attribute__((ext_vector_type(8))) short short8;           // 8 bf16
typedef __attribute__((ext_vector_type(8))) unsigned short ushort8;
typedef __attribute__((ext_vector_type(4))) float f32x4;
typedef __attribute__((ext_vector_type(2))) _Float16 half2v;
typedef __attribute__((ext_vector_type(4))) _Float16 half4;
typedef __attribute__((ext_vector_type(8))) _Float16 half8;

constexpr int Tc = 2048;
constexpr int Dc = 64;
constexpr size_t REGION = (size_t)32 * Tc * Dc;   // 4,194,304 elems = 8 MiB u16

__device__ inline unsigned short f2bf(float f) {   // fp32 -> bf16 RNE
    union { float f; unsigned u; } x; x.f = f;
    return (unsigned short)((x.u + 0x7fffu + ((x.u >> 16) & 1u)) >> 16);
}

__device__ inline half2v pkrtz(float a, float b) {
    return __builtin_bit_cast(half2v, __builtin_amdgcn_cvt_pkrtz(a, b));
}

#define MFMA_BF16_K32(a, b, c) __builtin_amdgcn_mfma_f32_16x16x32_bf16((a), (b), (c), 0, 0, 0)
#define MFMA_F16_K16(a, b, c)  __builtin_amdgcn_mfma_f32_16x16x16f16((a), (b), (c), 0, 0, 0)

// ---------------------------------------------------------------------------
// Kernel 0: C^T B-operand fragments per head (tiny, one-time).
// ---------------------------------------------------------------------------
__global__ __launch_bounds__(256, 1)
void holo_cfrag(const float* __restrict__ Cp, unsigned short* __restrict__ cfrag_g)
{
    const int t = threadIdx.x, lane = t & 63, eb = t >> 6;
    const int l15 = lane & 15, quad = lane >> 4;
    const int h = blockIdx.x;
    const float* Cg = Cp + (size_t)h * Dc * Dc;
    #pragma unroll
    for (int half = 0; half < 2; ++half) {
        short8 b;
        #pragma unroll
        for (int jj = 0; jj < 8; ++jj) {
            const int d = half * 32 + quad * 8 + jj;
            b[jj] = (short)f2bf(Cg[d * Dc + eb * 16 + l15]);
        }
        *(short8*)(&cfrag_g[(((size_t)h * 4 + eb) * 2 + half) * 512 + lane * 8]) = b;
    }
}

// ---------------------------------------------------------------------------
// Kernel 1: prepass, one block per (bh, 64-row tile st). LDS-staged.
// (unchanged)
// ---------------------------------------------------------------------------
__global__ __launch_bounds__(256, 4)
void holo_prep8(const float* __restrict__ Qp, const float* __restrict__ Kp,
                const float* __restrict__ Vp,
                const unsigned short* __restrict__ cfrag_g,
                unsigned short* __restrict__ qfrag_g,
                unsigned short* __restrict__ kfrag_g,
                _Float16* __restrict__ vfrag_g)
{
    __shared__ unsigned short kt[64 * 72];   // K tile bf16 natural [s][d]
    __shared__ unsigned short qt[64 * 72];   // Q tile bf16 natural [r][d]
    __shared__ _Float16      vt[64 * 72];    // V tile f16 natural [s][d]
    __shared__ unsigned short pf[64 * 72];   // Qrot C->B-frag round trip

    const int t = threadIdx.x, lane = t & 63, w = t >> 6;
    const int l15 = lane & 15, quad = lane >> 4, wb = w * 16;
    const int n = blockIdx.x, bh = n >> 5, st = n & 31, h = bh & 15;
    const int s0 = st * 64;

    const float* Qg = Qp + ((size_t)bh * Tc + s0) * Dc;
    const float* Kg = Kp + ((size_t)bh * Tc + s0) * Dc;
    const float* Vg = Vp + ((size_t)bh * Tc + s0) * Dc;

    // ---- stage all three tiles (coalesced float4 reads, cvt, LDS write) ----
    #pragma unroll
    for (int kk = 0; kk < 4; ++kk) {
        const int flat = kk * 1024 + t * 4;
        const int r = flat >> 6, d0 = flat & 63;
        float4 kv = *(const float4*)(&Kg[flat]);
        ushort4 kp; kp.x = f2bf(kv.x); kp.y = f2bf(kv.y); kp.z = f2bf(kv.z); kp.w = f2bf(kv.w);
        *(ushort4*)(&kt[r * 72 + d0]) = kp;
        float4 qv = *(const float4*)(&Qg[flat]);
        ushort4 qp; qp.x = f2bf(qv.x); qp.y = f2bf(qv.y); qp.z = f2bf(qv.z); qp.w = f2bf(qv.w);
        *(ushort4*)(&qt[r * 72 + d0]) = qp;
        float4 vv = *(const float4*)(&Vg[flat]);
        half4 vp;
        vp[0] = (_Float16)vv.x; vp[1] = (_Float16)vv.y;
        vp[2] = (_Float16)vv.z; vp[3] = (_Float16)vv.w;
        *(half4*)(&vt[r * 72 + d0]) = vp;
    }
    __syncthreads();

    // ---- K fragments (wave w handles tn = w): b128 LDS reads, coalesced writes
    {
        const int row = wb + l15;
        ushort8 p0 = *(const ushort8*)(&kt[row * 72 + quad * 8]);
        ushort8 p1 = *(const ushort8*)(&kt[row * 72 + 32 + quad * 8]);
        unsigned short* kdst = kfrag_g + (((size_t)(bh * 32 + st) * 4 + w) * 64 + lane) * 16;
        *(ushort8*)(kdst) = p0;
        *(ushort8*)(kdst + 8) = p1;
    }

    // ---- V fragments: scalar LDS reads (<=4-way banked), coalesced writes ----
    {
        half8 v0, v1;
        #pragma unroll
        for (int dn = 0; dn < 2; ++dn)
            #pragma unroll
            for (int i = 0; i < 4; ++i)
                v0[dn * 4 + i] = vt[(wb + quad * 4 + i) * 72 + dn * 16 + l15];
        #pragma unroll
        for (int dn = 0; dn < 2; ++dn)
            #pragma unroll
            for (int i = 0; i < 4; ++i)
                v1[dn * 4 + i] = vt[(wb + quad * 4 + i) * 72 + (dn + 2) * 16 + l15];
        _Float16* vdst = vfrag_g + (((size_t)(bh * 32 + st) * 4 + w) * 64 + lane) * 16;
        *(half8*)(vdst) = v0;
        *(half8*)(vdst + 8) = v1;
    }

    // ---- Qrot strip (rows s0+wb..+15): A from qt LDS, B from cfrag ----
    {
        short8 a0 = *(const short8*)(&qt[(wb + l15) * 72 + quad * 8]);
        short8 a1 = *(const short8*)(&qt[(wb + l15) * 72 + 32 + quad * 8]);
        #pragma unroll
        for (int eb = 0; eb < 4; ++eb) {
            short8 b0 = *(const short8*)(&cfrag_g[(((size_t)h * 4 + eb) * 2 + 0) * 512 + lane * 8]);
            short8 b1 = *(const short8*)(&cfrag_g[(((size_t)h * 4 + eb) * 2 + 1) * 512 + lane * 8]);
            f32x4 c = {0.f, 0.f, 0.f, 0.f};
            c = MFMA_BF16_K32(a0, b0, c);
            c = MFMA_BF16_K32(a1, b1, c);
            #pragma unroll
            for (int i = 0; i < 4; ++i)   // fold 0.125 * log2(e)
                pf[(wb + quad * 4 + i) * 72 + eb * 16 + l15] = f2bf(c[i] * 0.18033688f);
        }
        __threadfence_block();   // wave-local rows: order writes before reads
        short8 fa0 = *(const short8*)(&pf[(wb + l15) * 72 + quad * 8]);
        short8 fa1 = *(const short8*)(&pf[(wb + l15) * 72 + 32 + quad * 8]);
        const size_t strip = (size_t)bh * 128 + st * 4 + w;
        *(short8*)(&qfrag_g[strip * 1024 + lane * 8]) = fa0;
        *(short8*)(&qfrag_g[strip * 1024 + 512 + lane * 8]) = fa1;
    }
}

// ---------------------------------------------------------------------------
// Kernel 2: attention. 1 block = 1 (bh,qi) tile, 4 waves = (hv, parity).
// Round 11: strip-serial phases (lower liveness), 3 blocks/CU, setprio
// around MFMA clusters, guarded tail prefetch.
// ---------------------------------------------------------------------------
__global__ __launch_bounds__(256, 3)
void holo_attn11(const unsigned short* __restrict__ qfrag_g,
                 const unsigned short* __restrict__ kfrag_g,
                 const _Float16* __restrict__ vfrag_g,
                 float* __restrict__ Op)
{
    __shared__ float lds_o[2][2][16][68];   // [hv][s2][row][d] (+4 pad)
    __shared__ float lds_l[2][2][16];

    const int t = threadIdx.x, lane = t & 63, wid = t >> 6;
    const int l15 = lane & 15, quad = lane >> 4;
    const int hv  = wid & 1;      // row half: strips 2*hv, 2*hv+1
    const int par = wid >> 1;     // j parity

    // LPT + XCD-affine mapping: qi descends with dispatch order.
    const int id = blockIdx.x;
    const int xcd = id & 7, sseq = id >> 3;          // 128 blocks per XCD
    const int qi = 31 - (sseq >> 2);
    const int bh = xcd * 4 + (sseq & 3);
    const int q0 = qi * 64;

    // Qrot B-fragments for both strips (scale*log2e folded in)
    short8 qa0[2], qa1[2];
    #pragma unroll
    for (int s2 = 0; s2 < 2; ++s2) {
        const size_t strip = (size_t)bh * 128 + qi * 4 + (2 * hv + s2);
        qa0[s2] = *(const short8*)(&qfrag_g[strip * 1024 + lane * 8]);
        qa1[s2] = *(const short8*)(&qfrag_g[strip * 1024 + 512 + lane * 8]);
    }

    const unsigned short* kbase = kfrag_g + (size_t)bh * 32 * 4 * 1024;
    const _Float16*       vbase = vfrag_g + (size_t)bh * 32 * 4 * 1024;

    f32x4 o[2][4];                // o[s2][dn][i]: O[q=l15][d=dn*16+quad*4+i]
    #pragma unroll
    for (int s2 = 0; s2 < 2; ++s2)
        #pragma unroll
        for (int dn = 0; dn < 4; ++dn) o[s2][dn] = f32x4{0.f, 0.f, 0.f, 0.f};
    float l2[2] = {0.f, 0.f};

    const int rowgA = q0 + (2 * hv) * 16 + l15;   // strip 2hv global q row
    const int rowgB = rowgA + 16;                 // strip 2hv+1

    // preload K and V fragments for first tile j = par
    short8 kf0[4], kf1[4];
    half8 vlo[4], vhi[4];
    #pragma unroll
    for (int tn = 0; tn < 4; ++tn) {
        const unsigned short* kfb = kbase + (size_t)par * 4096 + ((size_t)tn * 64 + lane) * 16;
        kf0[tn] = *(const short8*)(kfb);
        kf1[tn] = *(const short8*)(kfb + 8);
        const _Float16* vfb = vbase + (size_t)par * 4096 + ((size_t)tn * 64 + lane) * 16;
        vlo[tn] = *(const half8*)(vfb);
        vhi[tn] = *(const half8*)(vfb + 8);
    }

    for (int j = par; j <= qi; j += 2) {
        const bool more = (j + 2 <= qi);
        const int jn = j + 2;

        // ---- S^T for both strips (K regs resident) ----
        f32x4 stA[4], stB[4];
        __builtin_amdgcn_s_setprio(1);
        #pragma unroll
        for (int tn = 0; tn < 4; ++tn) {
            f32x4 cA = {0.f, 0.f, 0.f, 0.f};
            cA = MFMA_BF16_K32(kf0[tn], qa0[0], cA);
            cA = MFMA_BF16_K32(kf1[tn], qa1[0], cA);
            stA[tn] = cA;
        }
        #pragma unroll
        for (int tn = 0; tn < 4; ++tn) {
            f32x4 cB = {0.f, 0.f, 0.f, 0.f};
            cB = MFMA_BF16_K32(kf0[tn], qa0[1], cB);
            cB = MFMA_BF16_K32(kf1[tn], qa1[1], cB);
            stB[tn] = cB;
        }
        __builtin_amdgcn_s_setprio(0);

        // ---- prefetch next tile's K (K regs just consumed) ----
        if (more) {
            #pragma unroll
            for (int tn = 0; tn < 4; ++tn) {
                const unsigned short* kfb = kbase + (size_t)jn * 4096 + ((size_t)tn * 64 + lane) * 16;
                kf0[tn] = *(const short8*)(kfb);
                kf1[tn] = *(const short8*)(kfb + 8);
            }
        }

        // ---- strip A: mask + exp2 + packed cvt, then PV ----
        {
            half4 paA[4];
            #pragma unroll
            for (int tn = 0; tn < 4; ++tn) {
                float p[4];
                #pragma unroll
                for (int i = 0; i < 4; ++i) {
                    float sv = stA[tn][i];
                    if (j == qi) {
                        const int colg = j * 64 + tn * 16 + quad * 4 + i;
                        if (colg > rowgA) sv = -1e30f;
                    }
                    p[i] = __builtin_amdgcn_exp2f(sv);
                    l2[0] += p[i];
                }
                half2v lo = pkrtz(p[0], p[1]), hi = pkrtz(p[2], p[3]);
                paA[tn] = __builtin_shufflevector(lo, hi, 0, 1, 2, 3);
            }
            __builtin_amdgcn_s_setprio(1);
            #pragma unroll
            for (int tn = 0; tn < 4; ++tn) {
                half4 vf0 = __builtin_shufflevector(vlo[tn], vlo[tn], 0, 1, 2, 3);
                half4 vf1 = __builtin_shufflevector(vlo[tn], vlo[tn], 4, 5, 6, 7);
                half4 vf2 = __builtin_shufflevector(vhi[tn], vhi[tn], 0, 1, 2, 3);
                half4 vf3 = __builtin_shufflevector(vhi[tn], vhi[tn], 4, 5, 6, 7);
                o[0][0] = MFMA_F16_K16(vf0, paA[tn], o[0][0]);
                o[0][1] = MFMA_F16_K16(vf1, paA[tn], o[0][1]);
                o[0][2] = MFMA_F16_K16(vf2, paA[tn], o[0][2]);
                o[0][3] = MFMA_F16_K16(vf3, paA[tn], o[0][3]);
            }
            __builtin_amdgcn_s_setprio(0);
        }

        // ---- strip B: mask + exp2 + packed cvt, then PV ----
        {
            half4 paB[4];
            #pragma unroll
            for (int tn = 0; tn < 4; ++tn) {
                float p[4];
                #pragma unroll
                for (int i = 0; i < 4; ++i) {
                    float sv = stB[tn][i];
                    if (j == qi) {
                        const int colg = j * 64 + tn * 16 + quad * 4 + i;
                        if (colg > rowgB) sv = -1e30f;
                    }
                    p[i] = __builtin_amdgcn_exp2f(sv);
                    l2[1] += p[i];
                }
                half2v lo = pkrtz(p[0], p[1]), hi = pkrtz(p[2], p[3]);
                paB[tn] = __builtin_shufflevector(lo, hi, 0, 1, 2, 3);
            }
            __builtin_amdgcn_s_setprio(1);
            #pragma unroll
            for (int tn = 0; tn < 4; ++tn) {
                half4 vf0 = __builtin_shufflevector(vlo[tn], vlo[tn], 0, 1, 2, 3);
                half4 vf1 = __builtin_shufflevector(vlo[tn], vlo[tn], 4, 5, 6, 7);
                half4 vf2 = __builtin_shufflevector(vhi[tn], vhi[tn], 0, 1, 2, 3);
                half4 vf3 = __builtin_shufflevector(vhi[tn], vhi[tn], 4, 5, 6, 7);
                o[1][0] = MFMA_F16_K16(vf0, paB[tn], o[1][0]);
                o[1][1] = MFMA_F16_K16(vf1, paB[tn], o[1][1]);
                o[1][2] = MFMA_F16_K16(vf2, paB[tn], o[1][2]);
                o[1][3] = MFMA_F16_K16(vf3, paB[tn], o[1][3]);
            }
            __builtin_amdgcn_s_setprio(0);
        }

        // ---- prefetch next tile's V (V regs just consumed) ----
        if (more) {
            #pragma unroll
            for (int tn = 0; tn < 4; ++tn) {
                const _Float16* vfb = vbase + (size_t)jn * 4096 + ((size_t)tn * 64 + lane) * 16;
                vlo[tn] = *(const half8*)(vfb);
                vhi[tn] = *(const half8*)(vfb + 8);
            }
        }
    }

    // ---- per-strip row sums (quad partials -> full row sum, all lanes) ----
    #pragma unroll
    for (int s2 = 0; s2 < 2; ++s2) {
        l2[s2] += __shfl_xor(l2[s2], 16);
        l2[s2] += __shfl_xor(l2[s2], 32);
    }

    // ---- combine parity partials: par==1 publishes, par==0 sums + stores ----
    if (par == 1) {
        #pragma unroll
        for (int s2 = 0; s2 < 2; ++s2) {
            #pragma unroll
            for (int dn = 0; dn < 4; ++dn) {
                float4 r;
                r.x = o[s2][dn][0]; r.y = o[s2][dn][1];
                r.z = o[s2][dn][2]; r.w = o[s2][dn][3];
                *(float4*)(&lds_o[hv][s2][l15][dn * 16 + quad * 4]) = r;
            }
            if (quad == 0) lds_l[hv][s2][l15] = l2[s2];
        }
    }
    __syncthreads();
    if (par == 0) {
        #pragma unroll
        for (int s2 = 0; s2 < 2; ++s2) {
            const float inv = 1.0f / (l2[s2] + lds_l[hv][s2][l15]);
            const int rowg = q0 + (2 * hv + s2) * 16 + l15;
            float* dst = Op + ((size_t)bh * Tc + rowg) * Dc;
            const float* po = &lds_o[hv][s2][l15][0];
            #pragma unroll
            for (int dn = 0; dn < 4; ++dn) {
                float4 r;
                r.x = (o[s2][dn][0] + po[dn * 16 + quad * 4 + 0]) * inv;
                r.y = (o[s2][dn][1] + po[dn * 16 + quad * 4 + 1]) * inv;
                r.z = (o[s2][dn][2] + po[dn * 16 + quad * 4 + 2]) * inv;
                r.w = (o[s2][dn][3] + po[dn * 16 + quad * 4 + 3]) * inv;
                *(float4*)(&dst[dn * 16 + quad * 4]) = r;
            }
        }
    }
}

extern "C" void kernel_launch(void* const* d_in, const int* in_sizes, int n_in,
                              void* d_out, int out_size, void* d_ws, size_t ws_size,
                              hipStream_t stream) {
    const float* Q = (const float*)d_in[0];
    const float* K = (const float*)d_in[1];
    const float* V = (const float*)d_in[2];
    // d_in[3] = causal mask (analytic — unused)
    const float* C = (const float*)d_in[4];
    float* O = (float*)d_out;

    unsigned short* qfrag_w = (unsigned short*)d_ws;              // 8 MiB
    unsigned short* kfrag_w = qfrag_w + REGION;                   // 8 MiB
    _Float16*       vfrag_w = (_Float16*)(kfrag_w + REGION);      // 8 MiB
    unsigned short* cfrag_w = (unsigned short*)(vfrag_w + REGION);// 128 KiB

    holo_cfrag<<<dim3(16), dim3(256), 0, stream>>>(C, cfrag_w);
    holo_prep8<<<dim3(1024), dim3(256), 0, stream>>>(Q, K, V, cfrag_w, qfrag_w, kfrag_w, vfrag_w);
    holo_attn11<<<dim3(1024), dim3(256), 0, stream>>>(qfrag_w, kfrag_w, vfrag_w, O);
}

// Round 3
// 136.297 us; speedup vs baseline: 1.2422x; 1.2422x over previous
//
#include <hip/hip_runtime.h>

// HolonomyAttention: out = softmax_causal((Q @ C_h) K^T / sqrt(D)) V
// B=2 H=16 T=2048 D=64, fp32 in/out.
// Round 12: revert to r10 structure (interleaved strips, bounds(256,2) --
// r11's bounds(256,3) spilled: VGPR 84, +33MB scratch writes/iter, 2x slow).
// Keep only the safe r11 deltas: guarded tail prefetch (kills 67MB wasted
// L2 reads) and s_setprio around MFMA clusters (T5, desynced waves).
// prep kernels unchanged.

typedef __attribute__((ext_vector_type(8))) short short8;           // 8 bf16
typedef __attribute__((ext_vector_type(8))) unsigned short ushort8;
typedef __attribute__((ext_vector_type(4))) float f32x4;
typedef __attribute__((ext_vector_type(2))) _Float16 half2v;
typedef __attribute__((ext_vector_type(4))) _Float16 half4;
typedef __attribute__((ext_vector_type(8))) _Float16 half8;

constexpr int Tc = 2048;
constexpr int Dc = 64;
constexpr size_t REGION = (size_t)32 * Tc * Dc;   // 4,194,304 elems = 8 MiB u16

__device__ inline unsigned short f2bf(float f) {   // fp32 -> bf16 RNE
    union { float f; unsigned u; } x; x.f = f;
    return (unsigned short)((x.u + 0x7fffu + ((x.u >> 16) & 1u)) >> 16);
}

__device__ inline half2v pkrtz(float a, float b) {
    return __builtin_bit_cast(half2v, __builtin_amdgcn_cvt_pkrtz(a, b));
}

#define MFMA_BF16_K32(a, b, c) __builtin_amdgcn_mfma_f32_16x16x32_bf16((a), (b), (c), 0, 0, 0)
#define MFMA_F16_K16(a, b, c)  __builtin_amdgcn_mfma_f32_16x16x16f16((a), (b), (c), 0, 0, 0)

// ---------------------------------------------------------------------------
// Kernel 0: C^T B-operand fragments per head (tiny, one-time).
// ---------------------------------------------------------------------------
__global__ __launch_bounds__(256, 1)
void holo_cfrag(const float* __restrict__ Cp, unsigned short* __restrict__ cfrag_g)
{
    const int t = threadIdx.x, lane = t & 63, eb = t >> 6;
    const int l15 = lane & 15, quad = lane >> 4;
    const int h = blockIdx.x;
    const float* Cg = Cp + (size_t)h * Dc * Dc;
    #pragma unroll
    for (int half = 0; half < 2; ++half) {
        short8 b;
        #pragma unroll
        for (int jj = 0; jj < 8; ++jj) {
            const int d = half * 32 + quad * 8 + jj;
            b[jj] = (short)f2bf(Cg[d * Dc + eb * 16 + l15]);
        }
        *(short8*)(&cfrag_g[(((size_t)h * 4 + eb) * 2 + half) * 512 + lane * 8]) = b;
    }
}

// ---------------------------------------------------------------------------
// Kernel 1: prepass, one block per (bh, 64-row tile st). LDS-staged.
// (unchanged)
// ---------------------------------------------------------------------------
__global__ __launch_bounds__(256, 4)
void holo_prep8(const float* __restrict__ Qp, const float* __restrict__ Kp,
                const float* __restrict__ Vp,
                const unsigned short* __restrict__ cfrag_g,
                unsigned short* __restrict__ qfrag_g,
                unsigned short* __restrict__ kfrag_g,
                _Float16* __restrict__ vfrag_g)
{
    __shared__ unsigned short kt[64 * 72];   // K tile bf16 natural [s][d]
    __shared__ unsigned short qt[64 * 72];   // Q tile bf16 natural [r][d]
    __shared__ _Float16      vt[64 * 72];    // V tile f16 natural [s][d]
    __shared__ unsigned short pf[64 * 72];   // Qrot C->B-frag round trip

    const int t = threadIdx.x, lane = t & 63, w = t >> 6;
    const int l15 = lane & 15, quad = lane >> 4, wb = w * 16;
    const int n = blockIdx.x, bh = n >> 5, st = n & 31, h = bh & 15;
    const int s0 = st * 64;

    const float* Qg = Qp + ((size_t)bh * Tc + s0) * Dc;
    const float* Kg = Kp + ((size_t)bh * Tc + s0) * Dc;
    const float* Vg = Vp + ((size_t)bh * Tc + s0) * Dc;

    // ---- stage all three tiles (coalesced float4 reads, cvt, LDS write) ----
    #pragma unroll
    for (int kk = 0; kk < 4; ++kk) {
        const int flat = kk * 1024 + t * 4;
        const int r = flat >> 6, d0 = flat & 63;
        float4 kv = *(const float4*)(&Kg[flat]);
        ushort4 kp; kp.x = f2bf(kv.x); kp.y = f2bf(kv.y); kp.z = f2bf(kv.z); kp.w = f2bf(kv.w);
        *(ushort4*)(&kt[r * 72 + d0]) = kp;
        float4 qv = *(const float4*)(&Qg[flat]);
        ushort4 qp; qp.x = f2bf(qv.x); qp.y = f2bf(qv.y); qp.z = f2bf(qv.z); qp.w = f2bf(qv.w);
        *(ushort4*)(&qt[r * 72 + d0]) = qp;
        float4 vv = *(const float4*)(&Vg[flat]);
        half4 vp;
        vp[0] = (_Float16)vv.x; vp[1] = (_Float16)vv.y;
        vp[2] = (_Float16)vv.z; vp[3] = (_Float16)vv.w;
        *(half4*)(&vt[r * 72 + d0]) = vp;
    }
    __syncthreads();

    // ---- K fragments (wave w handles tn = w): b128 LDS reads, coalesced writes
    {
        const int row = wb + l15;
        ushort8 p0 = *(const ushort8*)(&kt[row * 72 + quad * 8]);
        ushort8 p1 = *(const ushort8*)(&kt[row * 72 + 32 + quad * 8]);
        unsigned short* kdst = kfrag_g + (((size_t)(bh * 32 + st) * 4 + w) * 64 + lane) * 16;
        *(ushort8*)(kdst) = p0;
        *(ushort8*)(kdst + 8) = p1;
    }

    // ---- V fragments: scalar LDS reads (<=4-way banked), coalesced writes ----
    {
        half8 v0, v1;
        #pragma unroll
        for (int dn = 0; dn < 2; ++dn)
            #pragma unroll
            for (int i = 0; i < 4; ++i)
                v0[dn * 4 + i] = vt[(wb + quad * 4 + i) * 72 + dn * 16 + l15];
        #pragma unroll
        for (int dn = 0; dn < 2; ++dn)
            #pragma unroll
            for (int i = 0; i < 4; ++i)
                v1[dn * 4 + i] = vt[(wb + quad * 4 + i) * 72 + (dn + 2) * 16 + l15];
        _Float16* vdst = vfrag_g + (((size_t)(bh * 32 + st) * 4 + w) * 64 + lane) * 16;
        *(half8*)(vdst) = v0;
        *(half8*)(vdst + 8) = v1;
    }

    // ---- Qrot strip (rows s0+wb..+15): A from qt LDS, B from cfrag ----
    {
        short8 a0 = *(const short8*)(&qt[(wb + l15) * 72 + quad * 8]);
        short8 a1 = *(const short8*)(&qt[(wb + l15) * 72 + 32 + quad * 8]);
        #pragma unroll
        for (int eb = 0; eb < 4; ++eb) {
            short8 b0 = *(const short8*)(&cfrag_g[(((size_t)h * 4 + eb) * 2 + 0) * 512 + lane * 8]);
            short8 b1 = *(const short8*)(&cfrag_g[(((size_t)h * 4 + eb) * 2 + 1) * 512 + lane * 8]);
            f32x4 c = {0.f, 0.f, 0.f, 0.f};
            c = MFMA_BF16_K32(a0, b0, c);
            c = MFMA_BF16_K32(a1, b1, c);
            #pragma unroll
            for (int i = 0; i < 4; ++i)   // fold 0.125 * log2(e)
                pf[(wb + quad * 4 + i) * 72 + eb * 16 + l15] = f2bf(c[i] * 0.18033688f);
        }
        __threadfence_block();   // wave-local rows: order writes before reads
        short8 fa0 = *(const short8*)(&pf[(wb + l15) * 72 + quad * 8]);
        short8 fa1 = *(const short8*)(&pf[(wb + l15) * 72 + 32 + quad * 8]);
        const size_t strip = (size_t)bh * 128 + st * 4 + w;
        *(short8*)(&qfrag_g[strip * 1024 + lane * 8]) = fa0;
        *(short8*)(&qfrag_g[strip * 1024 + 512 + lane * 8]) = fa1;
    }
}

// ---------------------------------------------------------------------------
// Kernel 2: attention. 1 block = 1 (bh,qi) tile, 4 waves = (hv, parity).
// r10 structure: interleaved strip MFMA, combined softmax, reg prefetch,
// bounds(256,2). New: guarded tail prefetch + setprio around MFMA clusters.
// ---------------------------------------------------------------------------
__global__ __launch_bounds__(256, 2)
void holo_attn12(const unsigned short* __restrict__ qfrag_g,
                 const unsigned short* __restrict__ kfrag_g,
                 const _Float16* __restrict__ vfrag_g,
                 float* __restrict__ Op)
{
    __shared__ float lds_o[2][2][16][68];   // [hv][s2][row][d] (+4 pad)
    __shared__ float lds_l[2][2][16];

    const int t = threadIdx.x, lane = t & 63, wid = t >> 6;
    const int l15 = lane & 15, quad = lane >> 4;
    const int hv  = wid & 1;      // row half: strips 2*hv, 2*hv+1
    const int par = wid >> 1;     // j parity

    // LPT + XCD-affine mapping: qi descends with dispatch order.
    const int id = blockIdx.x;
    const int xcd = id & 7, sseq = id >> 3;          // 128 blocks per XCD
    const int qi = 31 - (sseq >> 2);
    const int bh = xcd * 4 + (sseq & 3);
    const int q0 = qi * 64;

    // Qrot B-fragments for both strips (scale*log2e folded in)
    short8 qa0[2], qa1[2];
    #pragma unroll
    for (int s2 = 0; s2 < 2; ++s2) {
        const size_t strip = (size_t)bh * 128 + qi * 4 + (2 * hv + s2);
        qa0[s2] = *(const short8*)(&qfrag_g[strip * 1024 + lane * 8]);
        qa1[s2] = *(const short8*)(&qfrag_g[strip * 1024 + 512 + lane * 8]);
    }

    const unsigned short* kbase = kfrag_g + (size_t)bh * 32 * 4 * 1024;
    const _Float16*       vbase = vfrag_g + (size_t)bh * 32 * 4 * 1024;

    f32x4 o[2][4];                // o[s2][dn][i]: O[q=l15][d=dn*16+quad*4+i]
    #pragma unroll
    for (int s2 = 0; s2 < 2; ++s2)
        #pragma unroll
        for (int dn = 0; dn < 4; ++dn) o[s2][dn] = f32x4{0.f, 0.f, 0.f, 0.f};
    float l2[2] = {0.f, 0.f};

    const int rowgA = q0 + (2 * hv) * 16 + l15;   // strip 2hv global q row
    const int rowgB = rowgA + 16;                 // strip 2hv+1

    // preload K and V fragments for first tile j = par
    short8 kf0[4], kf1[4];
    half8 vlo[4], vhi[4];
    #pragma unroll
    for (int tn = 0; tn < 4; ++tn) {
        const unsigned short* kfb = kbase + (size_t)par * 4096 + ((size_t)tn * 64 + lane) * 16;
        kf0[tn] = *(const short8*)(kfb);
        kf1[tn] = *(const short8*)(kfb + 8);
        const _Float16* vfb = vbase + (size_t)par * 4096 + ((size_t)tn * 64 + lane) * 16;
        vlo[tn] = *(const half8*)(vfb);
        vhi[tn] = *(const half8*)(vfb + 8);
    }

    for (int j = par; j <= qi; j += 2) {
        const bool more = (j + 2 <= qi);
        const int jn = j + 2;

        // ---- S^T = K * Qrot^T for both strips (K regs resident) ----
        f32x4 stA[4], stB[4];
        __builtin_amdgcn_s_setprio(1);
        #pragma unroll
        for (int tn = 0; tn < 4; ++tn) {
            f32x4 cA = {0.f, 0.f, 0.f, 0.f};
            cA = MFMA_BF16_K32(kf0[tn], qa0[0], cA);
            cA = MFMA_BF16_K32(kf1[tn], qa1[0], cA);
            stA[tn] = cA;
            f32x4 cB = {0.f, 0.f, 0.f, 0.f};
            cB = MFMA_BF16_K32(kf0[tn], qa0[1], cB);
            cB = MFMA_BF16_K32(kf1[tn], qa1[1], cB);
            stB[tn] = cB;
        }
        __builtin_amdgcn_s_setprio(0);

        // ---- prefetch next tile's K (in place; K regs just consumed) ----
        if (more) {
            #pragma unroll
            for (int tn = 0; tn < 4; ++tn) {
                const unsigned short* kfb = kbase + (size_t)jn * 4096 + ((size_t)tn * 64 + lane) * 16;
                kf0[tn] = *(const short8*)(kfb);
                kf1[tn] = *(const short8*)(kfb + 8);
            }
        }

        // ---- mask + fixed-shift softmax; packed f16 cvt into B-regs ----
        half4 paA[4], paB[4];
        #pragma unroll
        for (int tn = 0; tn < 4; ++tn) {
            float pA[4], pB[4];
            #pragma unroll
            for (int i = 0; i < 4; ++i) {
                float svA = stA[tn][i], svB = stB[tn][i];
                if (j == qi) {
                    const int colg = j * 64 + tn * 16 + quad * 4 + i;
                    if (colg > rowgA) svA = -1e30f;
                    if (colg > rowgB) svB = -1e30f;
                }
                pA[i] = __builtin_amdgcn_exp2f(svA);
                pB[i] = __builtin_amdgcn_exp2f(svB);
                l2[0] += pA[i];
                l2[1] += pB[i];
            }
            half2v loA = pkrtz(pA[0], pA[1]), hiA = pkrtz(pA[2], pA[3]);
            paA[tn] = __builtin_shufflevector(loA, hiA, 0, 1, 2, 3);
            half2v loB = pkrtz(pB[0], pB[1]), hiB = pkrtz(pB[2], pB[3]);
            paB[tn] = __builtin_shufflevector(loB, hiB, 0, 1, 2, 3);
        }

        // ---- O^T += V^T * P for both strips (V regs resident) ----
        __builtin_amdgcn_s_setprio(1);
        #pragma unroll
        for (int tn = 0; tn < 4; ++tn) {
            half4 vf0 = __builtin_shufflevector(vlo[tn], vlo[tn], 0, 1, 2, 3);
            half4 vf1 = __builtin_shufflevector(vlo[tn], vlo[tn], 4, 5, 6, 7);
            half4 vf2 = __builtin_shufflevector(vhi[tn], vhi[tn], 0, 1, 2, 3);
            half4 vf3 = __builtin_shufflevector(vhi[tn], vhi[tn], 4, 5, 6, 7);
            o[0][0] = MFMA_F16_K16(vf0, paA[tn], o[0][0]);
            o[0][1] = MFMA_F16_K16(vf1, paA[tn], o[0][1]);
            o[0][2] = MFMA_F16_K16(vf2, paA[tn], o[0][2]);
            o[0][3] = MFMA_F16_K16(vf3, paA[tn], o[0][3]);
            o[1][0] = MFMA_F16_K16(vf0, paB[tn], o[1][0]);
            o[1][1] = MFMA_F16_K16(vf1, paB[tn], o[1][1]);
            o[1][2] = MFMA_F16_K16(vf2, paB[tn], o[1][2]);
            o[1][3] = MFMA_F16_K16(vf3, paB[tn], o[1][3]);
        }
        __builtin_amdgcn_s_setprio(0);

        // ---- prefetch next tile's V (in place; V regs just consumed) ----
        if (more) {
            #pragma unroll
            for (int tn = 0; tn < 4; ++tn) {
                const _Float16* vfb = vbase + (size_t)jn * 4096 + ((size_t)tn * 64 + lane) * 16;
                vlo[tn] = *(const half8*)(vfb);
                vhi[tn] = *(const half8*)(vfb + 8);
            }
        }
    }

    // ---- per-strip row sums (quad partials -> full row sum, all lanes) ----
    #pragma unroll
    for (int s2 = 0; s2 < 2; ++s2) {
        l2[s2] += __shfl_xor(l2[s2], 16);
        l2[s2] += __shfl_xor(l2[s2], 32);
    }

    // ---- combine parity partials: par==1 publishes, par==0 sums + stores ----
    if (par == 1) {
        #pragma unroll
        for (int s2 = 0; s2 < 2; ++s2) {
            #pragma unroll
            for (int dn = 0; dn < 4; ++dn) {
                float4 r;
                r.x = o[s2][dn][0]; r.y = o[s2][dn][1];
                r.z = o[s2][dn][2]; r.w = o[s2][dn][3];
                *(float4*)(&lds_o[hv][s2][l15][dn * 16 + quad * 4]) = r;
            }
            if (quad == 0) lds_l[hv][s2][l15] = l2[s2];
        }
    }
    __syncthreads();
    if (par == 0) {
        #pragma unroll
        for (int s2 = 0; s2 < 2; ++s2) {
            const float inv = 1.0f / (l2[s2] + lds_l[hv][s2][l15]);
            const int rowg = q0 + (2 * hv + s2) * 16 + l15;
            float* dst = Op + ((size_t)bh * Tc + rowg) * Dc;
            const float* po = &lds_o[hv][s2][l15][0];
            #pragma unroll
            for (int dn = 0; dn < 4; ++dn) {
                float4 r;
                r.x = (o[s2][dn][0] + po[dn * 16 + quad * 4 + 0]) * inv;
                r.y = (o[s2][dn][1] + po[dn * 16 + quad * 4 + 1]) * inv;
                r.z = (o[s2][dn][2] + po[dn * 16 + quad * 4 + 2]) * inv;
                r.w = (o[s2][dn][3] + po[dn * 16 + quad * 4 + 3]) * inv;
                *(float4*)(&dst[dn * 16 + quad * 4]) = r;
            }
        }
    }
}

extern "C" void kernel_launch(void* const* d_in, const int* in_sizes, int n_in,
                              void* d_out, int out_size, void* d_ws, size_t ws_size,
                              hipStream_t stream) {
    const float* Q = (const float*)d_in[0];
    const float* K = (const float*)d_in[1];
    const float* V = (const float*)d_in[2];
    // d_in[3] = causal mask (analytic — unused)
    const float* C = (const float*)d_in[4];
    float* O = (float*)d_out;

    unsigned short* qfrag_w = (unsigned short*)d_ws;              // 8 MiB
    unsigned short* kfrag_w = qfrag_w + REGION;                   // 8 MiB
    _Float16*       vfrag_w = (_Float16*)(kfrag_w + REGION);      // 8 MiB
    unsigned short* cfrag_w = (unsigned short*)(vfrag_w + REGION);// 128 KiB

    holo_cfrag<<<dim3(16), dim3(256), 0, stream>>>(C, cfrag_w);
    holo_prep8<<<dim3(1024), dim3(256), 0, stream>>>(Q, K, V, cfrag_w, qfrag_w, kfrag_w, vfrag_w);
    holo_attn12<<<dim3(1024), dim3(256), 0, stream>>>(qfrag_w, kfrag_w, vfrag_w, O);
}